// Round 11
// baseline (2395.721 us; speedup 1.0000x reference)
//
#include <hip/hip_runtime.h>
#include <hip/hip_bf16.h>

#define BB 64
#define CC 32
#define HW2 256   // 16*16
#define VV 4096
#define NELEM (BB*CC*HW2)   // 524288
#define PADW 18
#define PADA 324  // 18*18

// ---------------- workspace layout (float offsets) ----------------
#define OFF_FHAT  0
#define OFF_EMBT  (OFF_FHAT  + NELEM)        // 524288 (tile-major codebook)
#define OFF_EMB   (OFF_EMBT  + VV*CC)        // 655360 (row-major codebook)
#define OFF_ESQ   (OFF_EMB   + VV*CC)        // 786432
#define OFF_PW    (OFF_ESQ   + VV)           // 790528
#define OFF_PB    (OFF_PW    + 4*CC*CC*9)    // 827392
#define OFF_REST  (OFF_PB    + 4*CC)         // 827520 (row-major, 16384*32)
#define OFF_BESTA (OFF_REST  + 16384*CC)     // 1351808 (16384 u64)
#define OFF_BESTB (OFF_BESTA + 2*16384)      // 1384576
#define OFF_LOSS  (OFF_BESTB + 2*16384)      // 1417344
#define OFF_FLAG  (OFF_LOSS  + 1)            // total ~5.67 MB (< proven 7.57)

// embT layout: embT[v>>6][c][v&63]  (tile stride 2048 floats, row stride 64)
__device__ __forceinline__ int embt_idx(int v, int c) {
    return (v >> 6) * 2048 + c * 64 + (v & 63);
}

__device__ __forceinline__ float decf(const void* fin, bool isf32, int i) {
    return isf32 ? ((const float*)fin)[i]
                 : __bfloat162float(((const __hip_bfloat16*)fin)[i]);
}

// ---------------- dtype probe: is input 0 f32 (1) or bf16 (0)? ----------------
__global__ void k_probe(const void* __restrict__ fin, int* __restrict__ flag) {
    __shared__ int cnt[256];
    int t = threadIdx.x;
    const __hip_bfloat16* p = (const __hip_bfloat16*)fin;
    int local = 0;
    for (int i = t; i < 8192; i += 256) {
        float v = __bfloat162float(p[i]);
        if (!(fabsf(v) < 1e3f)) local++;
    }
    cnt[t] = local;
    __syncthreads();
    for (int s = 128; s > 0; s >>= 1) {
        if (t < s) cnt[t] += cnt[t + s];
        __syncthreads();
    }
    if (t == 0) *flag = (cnt[0] >= 64) ? 1 : 0;
}

// ---------------- prep: decode codebook (both layouts) + weights; zero fhat ---
__global__ void k_prep(const void* __restrict__ ein,
                       const void* __restrict__ win,
                       const void* __restrict__ bin_,
                       const int* __restrict__ flag,
                       float* __restrict__ fhat,
                       float* __restrict__ embT, float* __restrict__ emb,
                       float* __restrict__ pw, float* __restrict__ pb,
                       float* __restrict__ loss) {
    bool isf32 = (*flag != 0);
    int i = blockIdx.x * 256 + threadIdx.x;
    if (i < NELEM) fhat[i] = 0.f;
    if (i < VV*CC) {
        float ev = isf32 ? ((const float*)ein)[i]
                         : __bfloat162float(((const __hip_bfloat16*)ein)[i]);
        int v = i >> 5, c = i & 31;
        embT[embt_idx(v, c)] = ev;
        emb[i] = ev;
    }
    if (i < 4*CC*CC*9)
        pw[i] = isf32 ? ((const float*)win)[i]
                      : __bfloat162float(((const __hip_bfloat16*)win)[i]);
    if (i < 4*CC)
        pb[i] = isf32 ? ((const float*)bin_)[i]
                      : __bfloat162float(((const __hip_bfloat16*)bin_)[i]);
    if (i == 0) *loss = 0.f;
}

__global__ void k_esq(const float* __restrict__ embT, float* __restrict__ esq) {
    int v = blockIdx.x * 256 + threadIdx.x;
    if (v >= VV) return;
    const float* p = embT + (v >> 6) * 2048 + (v & 63);
    float s = 0.f;
    #pragma unroll
    for (int c = 0; c < CC; ++c) { float e = p[c * 64]; s = fmaf(e, e, s); }
    esq[v] = s;
}

// ---------------- pool for scale 0 only (pn=1), init bestA --------------------
__global__ void k_pool0(const void* __restrict__ fin, const int* __restrict__ flag,
                        float* __restrict__ rest, unsigned long long* __restrict__ best) {
    int n = threadIdx.x;     // grid (1, 32)
    int c = blockIdx.y;
    if (n >= BB) return;
    bool isf32 = (*flag != 0);
    if (c == 0) best[n] = 0xFFFFFFFFFFFFFFFFull;
    int base = (n * CC + c) * HW2;
    float s = 0.f;
    for (int h = 0; h < 16; ++h)
        for (int w = 0; w < 16; ++w)
            s += decf(fin, isf32, base + h * 16 + w);   // fhat == 0 at scale 0
    rest[n * CC + c] = s * (1.f / 256.f);
}

// ---------------- argmin: LDS-tiled GEMM, 128 queries x 64-code tiles, K=32 ----
// Thread tile 8 queries x 4 codes. A-reads now 2x ds_read_b128 (xT stride 132
// rows are 16B-aligned: 132*4=528=33*16). Numerics identical to r8/r9 (passed).
__global__ __launch_bounds__(256)
void k_argmin(const float* __restrict__ rest, const float* __restrict__ embT,
              const float* __restrict__ esq, unsigned long long* __restrict__ best,
              int Ntot, int cpw) {
    __shared__ float xT[CC][132];    // [c][q], stride 132 (16B-aligned rows)
    __shared__ float eT[CC * 64];    // [c][64], matches embT tile layout
    __shared__ float xxs[2][128];
    int tid = threadIdx.x;
    int tx = tid & 15, ty = tid >> 4;
    int qblk = blockIdx.x * 128;
    int v0 = blockIdx.y * cpw;
    int t0 = v0 >> 6;

    // stage xT (transpose) + partial xx: thread = (query tid>>1, half tid&1)
    {
        int q = tid >> 1, h = tid & 1;
        int qq = qblk + q; if (qq > Ntot - 1) qq = Ntot - 1;
        const float* xr = rest + qq * CC + h * 16;
        float part = 0.f;
        #pragma unroll
        for (int c = 0; c < 16; ++c) {
            float xv = xr[c];
            xT[h * 16 + c][q] = xv;
            part = fmaf(xv, xv, part);
        }
        xxs[h][q] = part;
    }
    __syncthreads();

    float xx[8];
    #pragma unroll
    for (int i = 0; i < 8; ++i) {
        int q = ty * 8 + i;
        xx[i] = xxs[0][q] + xxs[1][q];
    }

    float bd[8]; int bi[8];
    #pragma unroll
    for (int i = 0; i < 8; ++i) { bd[i] = 3.4e38f; bi[i] = v0; }

    int ntiles = cpw >> 6;
    for (int t = 0; t < ntiles; ++t) {
        int vbase = v0 + t * 64;
        const float* gt = embT + (size_t)(t0 + t) * 2048;
        float4 s0 = *(const float4*)(gt + tid * 4);
        float4 s1 = *(const float4*)(gt + 1024 + tid * 4);
        __syncthreads();                     // prior tile's eT reads complete
        *(float4*)(eT + tid * 4) = s0;
        *(float4*)(eT + 1024 + tid * 4) = s1;
        __syncthreads();

        float acc[8][4];
        #pragma unroll
        for (int i = 0; i < 8; ++i)
            #pragma unroll
            for (int j = 0; j < 4; ++j) acc[i][j] = 0.f;

        #pragma unroll 8
        for (int k = 0; k < CC; ++k) {
            float4 a0 = *(const float4*)&xT[k][ty * 8];       // b128, broadcast
            float4 a1 = *(const float4*)&xT[k][ty * 8 + 4];   // b128, broadcast
            float4 b4 = *(const float4*)&eT[k * 64 + tx * 4]; // b128
            float a[8] = {a0.x, a0.y, a0.z, a0.w, a1.x, a1.y, a1.z, a1.w};
            float b[4] = {b4.x, b4.y, b4.z, b4.w};
            #pragma unroll
            for (int i = 0; i < 8; ++i)
                #pragma unroll
                for (int j = 0; j < 4; ++j)
                    acc[i][j] = fmaf(a[i], b[j], acc[i][j]);
        }

        float4 es4 = *(const float4*)(esq + vbase + tx * 4);   // L1-hot
        float es[4] = {es4.x, es4.y, es4.z, es4.w};
        #pragma unroll
        for (int i = 0; i < 8; ++i) {
            float base = xx[i];
            #pragma unroll
            for (int j = 0; j < 4; ++j) {
                float dist = fmaf(-2.f, acc[i][j], base + es[j]);
                if (dist < bd[i]) { bd[i] = dist; bi[i] = vbase + tx * 4 + j; }
            }
        }
    }

    #pragma unroll
    for (int i = 0; i < 8; ++i) {
        unsigned u = __float_as_uint(bd[i]);
        unsigned long long mono = (u & 0x80000000u)
            ? (unsigned long long)(~u)
            : (unsigned long long)(u | 0x80000000u);
        unsigned long long pk = (mono << 32) | (unsigned long long)(unsigned)bi[i];
        #pragma unroll
        for (int m = 1; m <= 8; m <<= 1) {
            unsigned long long o = __shfl_xor(pk, m, 64);
            if (o < pk) pk = o;
        }
        int q = qblk + ty * 8 + i;
        if (tx == 0 && q < Ntot)
            atomicMin(best + q, pk);
    }
}

// ---------------- fused: gather + upsample + conv3x3(phi) + f_hat + loss
//                  + pool(next scale) + best-init(next scale)
// 1024 threads: thread = (pixel, grp); grp stages 8 channels, computes 2 out-ch.
// Row-major emb gather (float4). Halo-padded LDS, border-only zeroing.
__global__ __launch_bounds__(1024)
void k_fuse(const float* __restrict__ emb,
            const unsigned long long* __restrict__ best,
            const float* __restrict__ pw, const float* __restrict__ pb,
            const void* __restrict__ fin, const int* __restrict__ flag,
            float* __restrict__ fhat,
            float* __restrict__ loss,
            float* __restrict__ rest,
            unsigned long long* __restrict__ best_next,
            int pn, int k, int pn_next) {
    __shared__ float h_pad[CC * PADA];  // [c][18*18], halo = zero padding
    __shared__ float extra[CC * 169];   // hs during upsample, then diff[8][256]
    __shared__ float red[16];
    int b = blockIdx.x, coq = blockIdx.y, t = threadIdx.x;
    bool isf32 = (*flag != 0);
    int nn = pn * pn;
    int pix = t & 255, grp = t >> 8;     // grp in 0..3
    int y = pix >> 4, x = pix & 15;
    int c0 = grp * 8;

    // zero border cells only (interior written below; disjoint -> no race)
    for (int i = t; i < CC * 68; i += 1024) {
        int c = i / 68, r = i % 68;
        int pos;
        if (r < 18)      pos = r;                       // top row
        else if (r < 36) pos = 17 * PADW + (r - 18);    // bottom row
        else if (r < 52) pos = (r - 35) * PADW;         // left col rows 1..16
        else             pos = (r - 51) * PADW + 17;    // right col rows 1..16
        h_pad[c * PADA + pos] = 0.f;
    }

    if (pn == 16) {
        int id = (int)(unsigned)(best[b * HW2 + pix] & 0xFFFFFFFFull);
        const float* er = emb + id * CC + c0;
        float4 e0 = *(const float4*)er;
        float4 e1 = *(const float4*)(er + 4);
        int ctr = (y + 1) * PADW + (x + 1);
        h_pad[(c0 + 0) * PADA + ctr] = e0.x;
        h_pad[(c0 + 1) * PADA + ctr] = e0.y;
        h_pad[(c0 + 2) * PADA + ctr] = e0.z;
        h_pad[(c0 + 3) * PADA + ctr] = e0.w;
        h_pad[(c0 + 4) * PADA + ctr] = e1.x;
        h_pad[(c0 + 5) * PADA + ctr] = e1.y;
        h_pad[(c0 + 6) * PADA + ctr] = e1.z;
        h_pad[(c0 + 7) * PADA + ctr] = e1.w;
    } else {
        float (*hs)[169] = (float(*)[169])extra;
        for (int q = t; q < nn * 4; q += 1024) {
            int cell = q >> 2, seg = q & 3;
            int id = (int)(unsigned)(best[b * nn + cell] & 0xFFFFFFFFull);
            const float* er = emb + id * CC + seg * 8;
            float4 e0 = *(const float4*)er;
            float4 e1 = *(const float4*)(er + 4);
            hs[seg * 8 + 0][cell] = e0.x;
            hs[seg * 8 + 1][cell] = e0.y;
            hs[seg * 8 + 2][cell] = e0.z;
            hs[seg * 8 + 3][cell] = e0.w;
            hs[seg * 8 + 4][cell] = e1.x;
            hs[seg * 8 + 5][cell] = e1.y;
            hs[seg * 8 + 6][cell] = e1.z;
            hs[seg * 8 + 7][cell] = e1.w;
        }
        __syncthreads();   // hs + border zeros visible
        float scale = (float)pn / 16.f;
        float sy = (y + 0.5f) * scale - 0.5f;
        sy = fminf(fmaxf(sy, 0.f), (float)(pn - 1));
        int y0 = (int)sy; int y1 = min(y0 + 1, pn - 1); float wy = sy - (float)y0;
        float sx = (x + 0.5f) * scale - 0.5f;
        sx = fminf(fmaxf(sx, 0.f), (float)(pn - 1));
        int x0 = (int)sx; int x1 = min(x0 + 1, pn - 1); float wx = sx - (float)x0;
        float wy0 = 1.f - wy, wx0 = 1.f - wx;
        int ctr = (y + 1) * PADW + (x + 1);
        #pragma unroll
        for (int c = 0; c < 8; ++c) {
            int cc = c0 + c;
            float v00 = hs[cc][y0 * pn + x0], v01 = hs[cc][y0 * pn + x1];
            float v10 = hs[cc][y1 * pn + x0], v11 = hs[cc][y1 * pn + x1];
            float a0 = wy0 * v00 + wy * v10;   // contract H first (jax resize order)
            float a1 = wy0 * v01 + wy * v11;
            h_pad[cc * PADA + ctr] = wx0 * a0 + wx * a1;
        }
    }
    __syncthreads();   // h_pad ready; all reads of hs/extra done

    float acc[2] = {0.f, 0.f};
    const float* hbase = h_pad + y * PADW + x;          // top-left neighbor
    const float* wpk = pw + (k * CC + coq * 8 + grp * 2) * (CC * 9);  // wave-uniform
    #pragma unroll
    for (int ci_ = 0; ci_ < CC; ++ci_) {
        float hv[9];
        #pragma unroll
        for (int dy = 0; dy < 3; ++dy)
            #pragma unroll
            for (int dx = 0; dx < 3; ++dx)
                hv[dy * 3 + dx] = hbase[ci_ * PADA + dy * PADW + dx];  // imm offsets
        const float* w0 = wpk + ci_ * 9;
        const float* w1 = w0 + CC * 9;
        #pragma unroll
        for (int q = 0; q < 9; ++q) {
            acc[0] = fmaf(hv[q], w0[q], acc[0]);
            acc[1] = fmaf(hv[q], w1[q], acc[1]);
        }
    }

    float* diff = extra;   // [8][256]
    float lsum = 0.f;
    int ctr = (y + 1) * PADW + (x + 1);
    #pragma unroll
    for (int o = 0; o < 2; ++o) {
        int lo = grp * 2 + o;
        int co = coq * 8 + lo;
        float hval = h_pad[co * PADA + ctr];
        float outv = hval * 0.5f + (acc[o] + pb[k * CC + co]) * 0.5f;
        int pos = (b * CC + co) * HW2 + pix;
        float fh = fhat[pos] + outv;
        fhat[pos] = fh;
        float dd = decf(fin, isf32, pos) - fh;   // loss AND next-scale pooling
        diff[lo * HW2 + pix] = dd;
        lsum = fmaf(dd, dd, lsum);
    }
    #pragma unroll
    for (int off = 32; off > 0; off >>= 1) lsum += __shfl_down(lsum, off, 64);
    if ((t & 63) == 0) red[t >> 6] = lsum;
    __syncthreads();   // red + diff visible
    if (t == 0) {
        float s = 0.f;
        #pragma unroll
        for (int w = 0; w < 16; ++w) s += red[w];
        atomicAdd(loss, s);
    }

    if (pn_next > 0) {
        int nn2 = pn_next * pn_next;
        for (int q = t; q < nn2 * 8; q += 1024) {
            int cell = q % nn2, o = q / nn2;
            int i = cell / pn_next, j = cell % pn_next;
            int s0 = (i * 16) / pn_next, e0 = ((i + 1) * 16 + pn_next - 1) / pn_next;
            int s1 = (j * 16) / pn_next, e1 = ((j + 1) * 16 + pn_next - 1) / pn_next;
            float inv = 1.f / (float)((e0 - s0) * (e1 - s1));
            float s = 0.f;
            for (int h = s0; h < e0; ++h)
                for (int w = s1; w < e1; ++w)
                    s += diff[o * HW2 + h * 16 + w];
            rest[(b * nn2 + cell) * CC + coq * 8 + o] = s * inv;   // row-major
        }
        if (coq == 0)
            for (int q = t; q < nn2; q += 1024)
                best_next[b * nn2 + q] = 0xFFFFFFFFFFFFFFFFull;
    }
}

// ---------------- writeout: f32 -> out dtype (matches probed input dtype) -----
__global__ void k_out(const float* __restrict__ fhat, const float* __restrict__ loss,
                      const int* __restrict__ flag, void* __restrict__ out) {
    bool isf32 = (*flag != 0);
    int i = blockIdx.x * 256 + threadIdx.x;
    if (i > NELEM) return;
    float v;
    if (i < NELEM) v = fhat[i];
    else           v = (*loss) * (1.25f / (float)NELEM / 8.f);
    if (isf32) ((float*)out)[i] = v;
    else       ((__hip_bfloat16*)out)[i] = __float2bfloat16(v);
}

extern "C" void kernel_launch(void* const* d_in, const int* in_sizes, int n_in,
                              void* d_out, int out_size, void* d_ws, size_t ws_size,
                              hipStream_t stream) {
    const void* fin  = d_in[0];
    const void* ein  = d_in[1];
    const void* win  = d_in[2];
    const void* bin_ = d_in[3];
    float* ws = (float*)d_ws;
    float* fhat = ws + OFF_FHAT;
    float* embT = ws + OFF_EMBT;
    float* emb  = ws + OFF_EMB;
    float* esq  = ws + OFF_ESQ;
    float* pw   = ws + OFF_PW;
    float* pb   = ws + OFF_PB;
    float* rest = ws + OFF_REST;
    unsigned long long* bestA = (unsigned long long*)(ws + OFF_BESTA);
    unsigned long long* bestB = (unsigned long long*)(ws + OFF_BESTB);
    float* loss = ws + OFF_LOSS;
    int*   flag = (int*)(ws + OFF_FLAG);

    static const int PN[8] = {1, 2, 4, 6, 8, 10, 13, 16};
    static const int KK[8] = {0, 0, 1, 1, 2, 2, 3, 3};
    static const int SP[8] = {64, 64, 64, 64, 32, 32, 16, 16};

    k_probe<<<1, 256, 0, stream>>>(fin, flag);
    k_prep<<<(NELEM + 255) / 256, 256, 0, stream>>>(ein, win, bin_, flag,
                                                    fhat, embT, emb, pw, pb, loss);
    k_esq<<<(VV + 255) / 256, 256, 0, stream>>>(embT, esq);
    k_pool0<<<dim3(1, CC), 256, 0, stream>>>(fin, flag, rest, bestA);

    for (int si = 0; si < 8; ++si) {
        int pn = PN[si];
        int Ntot = BB * pn * pn;
        int Sp = SP[si];
        int cpw = VV / Sp;
        unsigned long long* bcur = (si & 1) ? bestB : bestA;
        unsigned long long* bnxt = (si & 1) ? bestA : bestB;
        int pn_next = (si < 7) ? PN[si + 1] : 0;
        int gx = (Ntot + 127) / 128;
        k_argmin<<<dim3(gx, Sp), 256, 0, stream>>>(rest, embT, esq, bcur, Ntot, cpw);
        k_fuse<<<dim3(BB, 4), 1024, 0, stream>>>(emb, bcur, pw, pb, fin, flag, fhat,
                                                 loss, rest, bnxt, pn, KK[si], pn_next);
    }
    k_out<<<(NELEM + 1 + 255) / 256, 256, 0, stream>>>(fhat, loss, flag, d_out);
}

// Round 12
// 459.432 us; speedup vs baseline: 5.2145x; 5.2145x over previous
//
#include <hip/hip_runtime.h>
#include <hip/hip_bf16.h>

#define BB 64
#define CC 32
#define HW2 256   // 16*16
#define VV 4096
#define NELEM (BB*CC*HW2)   // 524288
#define PADW 18
#define PADA 324  // 18*18

// ---------------- workspace layout (float offsets) ----------------
#define OFF_F     0
#define OFF_FHAT  (OFF_F     + NELEM)        // 524288
#define OFF_EMBT  (OFF_FHAT  + NELEM)        // 1048576 (tile-major codebook)
#define OFF_ESQ   (OFF_EMBT  + VV*CC)        // 1179648
#define OFF_PW    (OFF_ESQ   + VV)           // 1183744
#define OFF_PB    (OFF_PW    + 4*CC*CC*9)    // 1220608
#define OFF_REST  (OFF_PB    + 4*CC)         // 1220736 (row-major, max 16384*32)
#define OFF_BESTA (OFF_REST  + 16384*CC)     // 1745024 (16384 u64)
#define OFF_BESTB (OFF_BESTA + 2*16384)      // 1777792
#define OFF_LOSS  (OFF_BESTB + 2*16384)      // 1810560
#define OFF_FLAG  (OFF_LOSS  + 1)            // total 7.24 MB < proven ws

// embT layout: embT[v>>6][c][v&63]  (tile stride 2048 floats, row stride 64)
__device__ __forceinline__ int embt_idx(int v, int c) {
    return (v >> 6) * 2048 + c * 64 + (v & 63);
}

// ---------------- dtype probe: is input 0 f32 (1) or bf16 (0)? ----------------
__global__ void k_probe(const void* __restrict__ fin, int* __restrict__ flag) {
    __shared__ int cnt[256];
    int t = threadIdx.x;
    const __hip_bfloat16* p = (const __hip_bfloat16*)fin;
    int local = 0;
    for (int i = t; i < 8192; i += 256) {
        float v = __bfloat162float(p[i]);
        if (!(fabsf(v) < 1e3f)) local++;
    }
    cnt[t] = local;
    __syncthreads();
    for (int s = 128; s > 0; s >>= 1) {
        if (t < s) cnt[t] += cnt[t + s];
        __syncthreads();
    }
    if (t == 0) *flag = (cnt[0] >= 64) ? 1 : 0;
}

// ---------------- prep: decode -> f32 ws (codebook into tile-major embT) ------
__global__ void k_prep(const void* __restrict__ fin,
                       const void* __restrict__ ein,
                       const void* __restrict__ win,
                       const void* __restrict__ bin_,
                       const int* __restrict__ flag,
                       float* __restrict__ f, float* __restrict__ fhat,
                       float* __restrict__ embT, float* __restrict__ pw,
                       float* __restrict__ pb, float* __restrict__ loss) {
    bool isf32 = (*flag != 0);
    int i = blockIdx.x * 256 + threadIdx.x;
    if (i < NELEM) {
        f[i] = isf32 ? ((const float*)fin)[i]
                     : __bfloat162float(((const __hip_bfloat16*)fin)[i]);
        fhat[i] = 0.f;
    }
    if (i < VV*CC) {
        float ev = isf32 ? ((const float*)ein)[i]
                         : __bfloat162float(((const __hip_bfloat16*)ein)[i]);
        int v = i >> 5, c = i & 31;
        embT[embt_idx(v, c)] = ev;
    }
    if (i < 4*CC*CC*9)
        pw[i] = isf32 ? ((const float*)win)[i]
                      : __bfloat162float(((const __hip_bfloat16*)win)[i]);
    if (i < 4*CC)
        pb[i] = isf32 ? ((const float*)bin_)[i]
                      : __bfloat162float(((const __hip_bfloat16*)bin_)[i]);
    if (i == 0) *loss = 0.f;
}

__global__ void k_esq(const float* __restrict__ embT, float* __restrict__ esq) {
    int v = blockIdx.x * 256 + threadIdx.x;
    if (v >= VV) return;
    const float* p = embT + (v >> 6) * 2048 + (v & 63);
    float s = 0.f;
    #pragma unroll
    for (int c = 0; c < CC; ++c) { float e = p[c * 64]; s = fmaf(e, e, s); }
    esq[v] = s;
}

// ---------------- pool for scale 0 only (pn=1), row-major rest, init bestA ----
__global__ void k_pool0(const float* __restrict__ f, const float* __restrict__ fhat,
                        float* __restrict__ rest, unsigned long long* __restrict__ best) {
    int n = threadIdx.x;     // grid (1, 32)
    int c = blockIdx.y;
    if (n >= BB) return;
    if (c == 0) best[n] = 0xFFFFFFFFFFFFFFFFull;
    const float* fb = f + (n * CC + c) * HW2;
    const float* hb = fhat + (n * CC + c) * HW2;
    float s = 0.f;
    for (int h = 0; h < 16; ++h)
        for (int w = 0; w < 16; ++w)
            s += fb[h * 16 + w] - hb[h * 16 + w];
    rest[n * CC + c] = s * (1.f / 256.f);
}

// ---------------- argmin: LDS-tiled GEMM, 128 queries x 64-code tiles, K=32 ----
// Thread tile 8 queries x 4 codes. A/B LDS reads via float4 (ds_read_b128):
// xT row stride 132 floats = 528 B = 33*16 -> rows 16B-aligned. Same values,
// same fma order as r8/r9 (passed). Merge: packed u64 atomicMin -> numpy ties.
__global__ __launch_bounds__(256)
void k_argmin(const float* __restrict__ rest, const float* __restrict__ embT,
              const float* __restrict__ esq, unsigned long long* __restrict__ best,
              int Ntot, int cpw) {
    __shared__ float xT[CC][132];    // [c][q], stride 132 (16B-aligned rows)
    __shared__ float eT[CC * 64];    // [c][64], matches embT tile layout
    __shared__ float xxs[2][128];
    int tid = threadIdx.x;
    int tx = tid & 15, ty = tid >> 4;
    int qblk = blockIdx.x * 128;
    int v0 = blockIdx.y * cpw;
    int t0 = v0 >> 6;

    // stage xT (transpose) + partial xx: thread = (query tid>>1, half tid&1)
    {
        int q = tid >> 1, h = tid & 1;
        int qq = qblk + q; if (qq > Ntot - 1) qq = Ntot - 1;
        const float* xr = rest + qq * CC + h * 16;
        float part = 0.f;
        #pragma unroll
        for (int c = 0; c < 16; ++c) {
            float xv = xr[c];
            xT[h * 16 + c][q] = xv;
            part = fmaf(xv, xv, part);
        }
        xxs[h][q] = part;
    }
    __syncthreads();

    float xx[8];
    #pragma unroll
    for (int i = 0; i < 8; ++i) {
        int q = ty * 8 + i;
        xx[i] = xxs[0][q] + xxs[1][q];
    }

    float bd[8]; int bi[8];
    #pragma unroll
    for (int i = 0; i < 8; ++i) { bd[i] = 3.4e38f; bi[i] = v0; }

    int ntiles = cpw >> 6;
    for (int t = 0; t < ntiles; ++t) {
        int vbase = v0 + t * 64;
        const float* gt = embT + (size_t)(t0 + t) * 2048;
        float4 s0 = *(const float4*)(gt + tid * 4);
        float4 s1 = *(const float4*)(gt + 1024 + tid * 4);
        __syncthreads();                     // prior tile's eT reads complete
        *(float4*)(eT + tid * 4) = s0;
        *(float4*)(eT + 1024 + tid * 4) = s1;
        __syncthreads();

        float acc[8][4];
        #pragma unroll
        for (int i = 0; i < 8; ++i)
            #pragma unroll
            for (int j = 0; j < 4; ++j) acc[i][j] = 0.f;

        #pragma unroll 8
        for (int k = 0; k < CC; ++k) {
            float4 a0 = *(const float4*)&xT[k][ty * 8];       // b128 broadcast
            float4 a1 = *(const float4*)&xT[k][ty * 8 + 4];   // b128 broadcast
            float4 b4 = *(const float4*)&eT[k * 64 + tx * 4]; // b128
            float a[8] = {a0.x, a0.y, a0.z, a0.w, a1.x, a1.y, a1.z, a1.w};
            float b[4] = {b4.x, b4.y, b4.z, b4.w};
            #pragma unroll
            for (int i = 0; i < 8; ++i)
                #pragma unroll
                for (int j = 0; j < 4; ++j)
                    acc[i][j] = fmaf(a[i], b[j], acc[i][j]);
        }

        float4 es4 = *(const float4*)(esq + vbase + tx * 4);   // L1-hot
        float es[4] = {es4.x, es4.y, es4.z, es4.w};
        #pragma unroll
        for (int i = 0; i < 8; ++i) {
            float base = xx[i];
            #pragma unroll
            for (int j = 0; j < 4; ++j) {
                float dist = fmaf(-2.f, acc[i][j], base + es[j]);
                if (dist < bd[i]) { bd[i] = dist; bi[i] = vbase + tx * 4 + j; }
            }
        }
    }

    #pragma unroll
    for (int i = 0; i < 8; ++i) {
        unsigned u = __float_as_uint(bd[i]);
        unsigned long long mono = (u & 0x80000000u)
            ? (unsigned long long)(~u)
            : (unsigned long long)(u | 0x80000000u);
        unsigned long long pk = (mono << 32) | (unsigned long long)(unsigned)bi[i];
        #pragma unroll
        for (int m = 1; m <= 8; m <<= 1) {
            unsigned long long o = __shfl_xor(pk, m, 64);
            if (o < pk) pk = o;
        }
        int q = qblk + ty * 8 + i;
        if (tx == 0 && q < Ntot)
            atomicMin(best + q, pk);
    }
}

// ---------------- fused: gather + upsample + conv3x3(phi) + f_hat + loss
//                  + pool(next scale) + best-init(next scale)
// grid (64,8) x 256 threads: block = (batch, 4-out-channel octant).
// Same per-thread body as r9 (proven, no spill); double block-level parallelism.
__global__ __launch_bounds__(256)
void k_fuse(const float* __restrict__ embT,
            const unsigned long long* __restrict__ best,
            const float* __restrict__ pw, const float* __restrict__ pb,
            const float* __restrict__ f, float* __restrict__ fhat,
            float* __restrict__ loss,
            float* __restrict__ rest,
            unsigned long long* __restrict__ best_next,
            int pn, int k, int pn_next) {
    __shared__ float h_pad[CC * PADA];  // [c][18*18], halo = zero padding
    __shared__ float extra[CC * 169];   // hs during upsample, then diff[4][256]
    __shared__ float red[4];
    int b = blockIdx.x, co8 = blockIdx.y, t = threadIdx.x;
    int nn = pn * pn;
    int y = t >> 4, x = t & 15;

    // zero h_pad (covers halo; interior overwritten after a barrier)
    for (int i = t; i < CC * PADA; i += 256) h_pad[i] = 0.f;

    if (pn == 16) {
        __syncthreads();   // zeros visible before interior fill
        int id = (int)(unsigned)(best[b * HW2 + t] & 0xFFFFFFFFull);
        const float* er = embT + (id >> 6) * 2048 + (id & 63);
        int ctr = (y + 1) * PADW + (x + 1);
        #pragma unroll
        for (int c = 0; c < CC; ++c)
            h_pad[c * PADA + ctr] = er[c * 64];
    } else {
        float (*hs)[169] = (float(*)[169])extra;
        for (int cell = t; cell < nn; cell += 256) {
            int id = (int)(unsigned)(best[b * nn + cell] & 0xFFFFFFFFull);
            const float* er = embT + (id >> 6) * 2048 + (id & 63);
            #pragma unroll
            for (int c = 0; c < CC; ++c) hs[c][cell] = er[c * 64];
        }
        __syncthreads();   // zeros + hs visible
        float scale = (float)pn / 16.f;
        float sy = (y + 0.5f) * scale - 0.5f;
        sy = fminf(fmaxf(sy, 0.f), (float)(pn - 1));
        int y0 = (int)sy; int y1 = min(y0 + 1, pn - 1); float wy = sy - (float)y0;
        float sx = (x + 0.5f) * scale - 0.5f;
        sx = fminf(fmaxf(sx, 0.f), (float)(pn - 1));
        int x0 = (int)sx; int x1 = min(x0 + 1, pn - 1); float wx = sx - (float)x0;
        float wy0 = 1.f - wy, wx0 = 1.f - wx;
        int ctr = (y + 1) * PADW + (x + 1);
        #pragma unroll
        for (int c = 0; c < CC; ++c) {
            float v00 = hs[c][y0 * pn + x0], v01 = hs[c][y0 * pn + x1];
            float v10 = hs[c][y1 * pn + x0], v11 = hs[c][y1 * pn + x1];
            float a0 = wy0 * v00 + wy * v10;   // contract H first (jax resize order)
            float a1 = wy0 * v01 + wy * v11;
            h_pad[c * PADA + ctr] = wx0 * a0 + wx * a1;
        }
    }
    __syncthreads();   // h_pad ready; all reads of hs/extra done

    float acc[4];
    #pragma unroll
    for (int o = 0; o < 4; ++o) acc[o] = 0.f;
    const float* hbase = h_pad + y * PADW + x;          // top-left neighbor
    const float* wpk = pw + (k * CC + co8 * 4) * (CC * 9);   // block-uniform
    #pragma unroll
    for (int ci_ = 0; ci_ < CC; ++ci_) {
        float hv[9];
        #pragma unroll
        for (int dy = 0; dy < 3; ++dy)
            #pragma unroll
            for (int dx = 0; dx < 3; ++dx)
                hv[dy * 3 + dx] = hbase[ci_ * PADA + dy * PADW + dx];  // imm offsets
        const float* wp = wpk + ci_ * 9;
        #pragma unroll
        for (int o = 0; o < 4; ++o) {
            const float* w9 = wp + o * (CC * 9);
            #pragma unroll
            for (int q = 0; q < 9; ++q) acc[o] = fmaf(hv[q], w9[q], acc[o]);
        }
    }

    float* diff = extra;   // [4][256], safe: extra unread after the h_pad barrier
    float lsum = 0.f;
    int ctr = (y + 1) * PADW + (x + 1);
    #pragma unroll
    for (int o = 0; o < 4; ++o) {
        int co = co8 * 4 + o;
        float hval = h_pad[co * PADA + ctr];
        float outv = hval * 0.5f + (acc[o] + pb[k * CC + co]) * 0.5f;
        int pos = (b * CC + co) * HW2 + t;
        float fh = fhat[pos] + outv;
        fhat[pos] = fh;
        float dd = f[pos] - fh;        // used for loss AND next-scale pooling
        diff[o * HW2 + t] = dd;
        lsum = fmaf(dd, dd, lsum);
    }
    #pragma unroll
    for (int off = 32; off > 0; off >>= 1) lsum += __shfl_down(lsum, off, 64);
    if ((t & 63) == 0) red[t >> 6] = lsum;
    __syncthreads();   // red + diff visible
    if (t == 0)
        atomicAdd(loss, red[0] + red[1] + red[2] + red[3]);

    if (pn_next > 0) {
        int nn2 = pn_next * pn_next;
        for (int q = t; q < nn2 * 4; q += 256) {
            int cell = q % nn2, o = q / nn2;
            int i = cell / pn_next, j = cell % pn_next;
            int s0 = (i * 16) / pn_next, e0 = ((i + 1) * 16 + pn_next - 1) / pn_next;
            int s1 = (j * 16) / pn_next, e1 = ((j + 1) * 16 + pn_next - 1) / pn_next;
            float inv = 1.f / (float)((e0 - s0) * (e1 - s1));
            float s = 0.f;
            for (int h = s0; h < e0; ++h)
                for (int w = s1; w < e1; ++w)
                    s += diff[o * HW2 + h * 16 + w];
            rest[(b * nn2 + cell) * CC + co8 * 4 + o] = s * inv;   // row-major
        }
        if (co8 == 0)
            for (int q = t; q < nn2; q += 256)
                best_next[b * nn2 + q] = 0xFFFFFFFFFFFFFFFFull;
    }
}

// ---------------- writeout: f32 -> out dtype (matches probed input dtype) -----
__global__ void k_out(const float* __restrict__ fhat, const float* __restrict__ loss,
                      const int* __restrict__ flag, void* __restrict__ out) {
    bool isf32 = (*flag != 0);
    int i = blockIdx.x * 256 + threadIdx.x;
    if (i > NELEM) return;
    float v;
    if (i < NELEM) v = fhat[i];
    else           v = (*loss) * (1.25f / (float)NELEM / 8.f);
    if (isf32) ((float*)out)[i] = v;
    else       ((__hip_bfloat16*)out)[i] = __float2bfloat16(v);
}

extern "C" void kernel_launch(void* const* d_in, const int* in_sizes, int n_in,
                              void* d_out, int out_size, void* d_ws, size_t ws_size,
                              hipStream_t stream) {
    const void* fin  = d_in[0];
    const void* ein  = d_in[1];
    const void* win  = d_in[2];
    const void* bin_ = d_in[3];
    float* ws = (float*)d_ws;
    float* f    = ws + OFF_F;
    float* fhat = ws + OFF_FHAT;
    float* embT = ws + OFF_EMBT;
    float* esq  = ws + OFF_ESQ;
    float* pw   = ws + OFF_PW;
    float* pb   = ws + OFF_PB;
    float* rest = ws + OFF_REST;
    unsigned long long* bestA = (unsigned long long*)(ws + OFF_BESTA);
    unsigned long long* bestB = (unsigned long long*)(ws + OFF_BESTB);
    float* loss = ws + OFF_LOSS;
    int*   flag = (int*)(ws + OFF_FLAG);

    static const int PN[8] = {1, 2, 4, 6, 8, 10, 13, 16};
    static const int KK[8] = {0, 0, 1, 1, 2, 2, 3, 3};
    static const int SP[8] = {64, 64, 64, 64, 32, 32, 16, 16};

    k_probe<<<1, 256, 0, stream>>>(fin, flag);
    k_prep<<<(NELEM + 255) / 256, 256, 0, stream>>>(fin, ein, win, bin_, flag,
                                                    f, fhat, embT, pw, pb, loss);
    k_esq<<<(VV + 255) / 256, 256, 0, stream>>>(embT, esq);
    k_pool0<<<dim3(1, CC), 256, 0, stream>>>(f, fhat, rest, bestA);

    for (int si = 0; si < 8; ++si) {
        int pn = PN[si];
        int Ntot = BB * pn * pn;
        int Sp = SP[si];
        int cpw = VV / Sp;
        unsigned long long* bcur = (si & 1) ? bestB : bestA;
        unsigned long long* bnxt = (si & 1) ? bestA : bestB;
        int pn_next = (si < 7) ? PN[si + 1] : 0;
        int gx = (Ntot + 127) / 128;
        k_argmin<<<dim3(gx, Sp), 256, 0, stream>>>(rest, embT, esq, bcur, Ntot, cpw);
        k_fuse<<<dim3(BB, 8), 256, 0, stream>>>(embT, bcur, pw, pb, f, fhat, loss,
                                                rest, bnxt, pn, KK[si], pn_next);
    }
    k_out<<<(NELEM + 1 + 255) / 256, 256, 0, stream>>>(fhat, loss, flag, d_out);
}